// Round 1
// baseline (219.651 us; speedup 1.0000x reference)
//
#include <hip/hip_runtime.h>

#define SEQ 4096
#define DM 1024
#define NH 16
#define DK 64

typedef _Float16 half8 __attribute__((ext_vector_type(8)));
typedef _Float16 half4v __attribute__((ext_vector_type(4)));
typedef float f32x4 __attribute__((ext_vector_type(4)));

#define MFMA16(a, b, c) __builtin_amdgcn_mfma_f32_16x16x32_f16((a), (b), (c), 0, 0, 0)

// ---------------- fp32 -> fp16 conversion (7 tensors in one launch) ----------------
__global__ void cvt_all(const float* __restrict__ q, const float* __restrict__ k,
                        const float* __restrict__ v, const float* __restrict__ wq,
                        const float* __restrict__ wk, const float* __restrict__ wv,
                        const float* __restrict__ wo, _Float16* __restrict__ qh,
                        _Float16* __restrict__ kh, _Float16* __restrict__ vh,
                        _Float16* __restrict__ wqh, _Float16* __restrict__ wkh,
                        _Float16* __restrict__ wvh, _Float16* __restrict__ woh) {
    int z = blockIdx.y;
    const float* src;
    _Float16* dst;
    int n;
    switch (z) {
    case 0: src = q;  dst = qh;  n = SEQ * DM; break;
    case 1: src = k;  dst = kh;  n = SEQ * DM; break;
    case 2: src = v;  dst = vh;  n = SEQ * DM; break;
    case 3: src = wq; dst = wqh; n = DM * DM;  break;
    case 4: src = wk; dst = wkh; n = DM * DM;  break;
    case 5: src = wv; dst = wvh; n = DM * DM;  break;
    default: src = wo; dst = woh; n = DM * DM; break;
    }
    int idx = (blockIdx.x * 256 + threadIdx.x) * 4;
    if (idx >= n) return;
    float4 f = *(const float4*)(src + idx);
    half4v h;
    h[0] = (_Float16)f.x; h[1] = (_Float16)f.y; h[2] = (_Float16)f.z; h[3] = (_Float16)f.w;
    *(half4v*)(dst + idx) = h;
}

// ---------------- m97-style f16 GEMM core: C = A @ B^T + bias ----------------
// A[M,K] row-major f16, B[N,K] row-major f16 (i.e. x @ W.T), K=N=1024, M=4096.
// mode 0: f16 out row-major, (acc+bias)*scale
// mode 1: f16 out transposed [N][M] pitch SEQ (per-head-transposed V)
// mode 2: fp32 out row-major, acc+bias
__device__ __forceinline__ void gemm128_core(const _Float16* __restrict__ A,
                                             const _Float16* __restrict__ B,
                                             const float* __restrict__ bias,
                                             void* __restrict__ Cout, int mode, float scale) {
    const int K = DM;
    const int N = DM;
    __shared__ _Float16 As[128 * 32];
    __shared__ _Float16 Bs[128 * 32];
    int tid = threadIdx.x;
    int wave = tid >> 6, lane = tid & 63;
    int quad = lane >> 4, l16 = lane & 15;
    int m0 = blockIdx.x * 128;
    int n0 = blockIdx.y * 128;
    int wr = (wave >> 1) * 64;
    int wc = (wave & 1) * 64;
    f32x4 acc[4][4] = {};
    int c0 = wave * 64 + lane;

    for (int k0 = 0; k0 < K; k0 += 32) {
#pragma unroll
        for (int j = 0; j < 2; ++j) {
            int c = c0 + j * 256;
            int row = c >> 2, cc = c & 3;
            const _Float16* ga = A + (size_t)(m0 + row) * K + k0 + cc * 8;
            const _Float16* gb = B + (size_t)(n0 + row) * K + k0 + cc * 8;
            __builtin_amdgcn_global_load_lds(
                (const __attribute__((address_space(1))) void*)ga,
                (__attribute__((address_space(3))) void*)(As + j * 2048 + wave * 512), 16, 0, 0);
            __builtin_amdgcn_global_load_lds(
                (const __attribute__((address_space(1))) void*)gb,
                (__attribute__((address_space(3))) void*)(Bs + j * 2048 + wave * 512), 16, 0, 0);
        }
        __syncthreads();
        half8 af[4], bf[4];
#pragma unroll
        for (int mi = 0; mi < 4; ++mi)
            af[mi] = *(const half8*)&As[(wr + mi * 16 + l16) * 32 + quad * 8];
#pragma unroll
        for (int ni = 0; ni < 4; ++ni)
            bf[ni] = *(const half8*)&Bs[(wc + ni * 16 + l16) * 32 + quad * 8];
#pragma unroll
        for (int mi = 0; mi < 4; ++mi)
#pragma unroll
            for (int ni = 0; ni < 4; ++ni)
                acc[mi][ni] = MFMA16(af[mi], bf[ni], acc[mi][ni]);
        __syncthreads();
    }

    float bs[4];
#pragma unroll
    for (int ni = 0; ni < 4; ++ni) bs[ni] = bias[n0 + wc + ni * 16 + l16];

    if (mode == 0) {
        _Float16* C = (_Float16*)Cout;
#pragma unroll
        for (int mi = 0; mi < 4; ++mi)
#pragma unroll
            for (int ni = 0; ni < 4; ++ni) {
                int m = m0 + wr + mi * 16 + quad * 4;
                int n = n0 + wc + ni * 16 + l16;
#pragma unroll
                for (int r = 0; r < 4; ++r)
                    C[(size_t)(m + r) * N + n] = (_Float16)((acc[mi][ni][r] + bs[ni]) * scale);
            }
    } else if (mode == 1) {
        _Float16* C = (_Float16*)Cout;
#pragma unroll
        for (int mi = 0; mi < 4; ++mi)
#pragma unroll
            for (int ni = 0; ni < 4; ++ni) {
                int m = m0 + wr + mi * 16 + quad * 4;
                int n = n0 + wc + ni * 16 + l16;
                half4v p;
#pragma unroll
                for (int r = 0; r < 4; ++r) p[r] = (_Float16)(acc[mi][ni][r] + bs[ni]);
                *(half4v*)(C + (size_t)n * SEQ + m) = p;  // m % 4 == 0 -> 8B aligned
            }
    } else {
        float* C = (float*)Cout;
#pragma unroll
        for (int mi = 0; mi < 4; ++mi)
#pragma unroll
            for (int ni = 0; ni < 4; ++ni) {
                int m = m0 + wr + mi * 16 + quad * 4;
                int n = n0 + wc + ni * 16 + l16;
#pragma unroll
                for (int r = 0; r < 4; ++r)
                    C[(size_t)(m + r) * N + n] = acc[mi][ni][r] + bs[ni];
            }
    }
}

__global__ void gemm_qkv(const _Float16* __restrict__ qh, const _Float16* __restrict__ kh,
                         const _Float16* __restrict__ vh, const _Float16* __restrict__ wqh,
                         const _Float16* __restrict__ wkh, const _Float16* __restrict__ wvh,
                         const float* __restrict__ bq, const float* __restrict__ bk,
                         const float* __restrict__ bv, _Float16* __restrict__ Qo,
                         _Float16* __restrict__ Ko, _Float16* __restrict__ Vt) {
    int z = blockIdx.z;
    const _Float16 *A, *B;
    const float* bias;
    void* C;
    int mode;
    float scale;
    if (z == 0) { A = qh; B = wqh; bias = bq; C = Qo; mode = 0; scale = 0.125f; }  // 1/sqrt(64)
    else if (z == 1) { A = kh; B = wkh; bias = bk; C = Ko; mode = 0; scale = 1.0f; }
    else { A = vh; B = wvh; bias = bv; C = Vt; mode = 1; scale = 1.0f; }
    gemm128_core(A, B, bias, C, mode, scale);
}

__global__ void gemm_out(const _Float16* __restrict__ Xh, const _Float16* __restrict__ woh,
                         const float* __restrict__ bo, float* __restrict__ out) {
    gemm128_core(Xh, woh, bo, out, 2, 1.0f);
}

// ---------------- windowed attention, flash-style online softmax ----------------
// One wave = 16 queries of one head. Q pre-scaled by 1/8. Vt is [DM][SEQ] (per-head V^T).
__global__ void attn_kernel(const _Float16* __restrict__ Q, const _Float16* __restrict__ K,
                            const _Float16* __restrict__ Vt, _Float16* __restrict__ X) {
    __shared__ _Float16 Pl[4][16][32];
    int tid = threadIdx.x;
    int wave = tid >> 6, lane = tid & 63;
    int quad = lane >> 4, l16 = lane & 15;
    int h = blockIdx.y;
    int q0 = blockIdx.x * 64 + wave * 16;

    const _Float16* Qp = Q + (size_t)(q0 + l16) * DM + h * DK + quad * 8;
    half8 aq0 = *(const half8*)(Qp);
    half8 aq1 = *(const half8*)(Qp + 32);

    float rowM[4], rowL[4];
    f32x4 o[4] = {};
#pragma unroll
    for (int r = 0; r < 4; ++r) { rowM[r] = -__builtin_inff(); rowL[r] = 0.f; }

    int kstart = (q0 > 127) ? ((q0 - 127) & ~31) : 0;
    int kend = q0 + 143;
    if (kend > SEQ - 1) kend = SEQ - 1;

    for (int kt = kstart; kt <= kend; kt += 32) {
        f32x4 s[2];
#pragma unroll
        for (int cf = 0; cf < 2; ++cf) {
            int krow = kt + cf * 16 + l16;  // always < SEQ (32-aligned tiles, SEQ % 32 == 0)
            const _Float16* Kp = K + (size_t)krow * DM + h * DK + quad * 8;
            half8 b0 = *(const half8*)(Kp);
            half8 b1 = *(const half8*)(Kp + 32);
            f32x4 z = {};
            z = MFMA16(aq0, b0, z);
            z = MFMA16(aq1, b1, z);
            s[cf] = z;
        }
        float mnew[4], alpha[4];
#pragma unroll
        for (int r = 0; r < 4; ++r) {
            int row = q0 + quad * 4 + r;
#pragma unroll
            for (int cf = 0; cf < 2; ++cf) {
                int key = kt + cf * 16 + l16;
                bool valid = (key >= row - 127) && (key <= row + 128);
                if (!valid) s[cf][r] = -1e30f;
            }
            float t = fmaxf(s[0][r], s[1][r]);
#pragma unroll
            for (int off = 1; off < 16; off <<= 1) t = fmaxf(t, __shfl_xor(t, off));
            mnew[r] = fmaxf(rowM[r], t);
            alpha[r] = __expf(rowM[r] - mnew[r]);  // exp(-inf - finite) = 0 on first tile
            float p0 = __expf(s[0][r] - mnew[r]);
            float p1 = __expf(s[1][r] - mnew[r]);
            Pl[wave][quad * 4 + r][l16] = (_Float16)p0;
            Pl[wave][quad * 4 + r][l16 + 16] = (_Float16)p1;
            float rs = p0 + p1;
#pragma unroll
            for (int off = 1; off < 16; off <<= 1) rs += __shfl_xor(rs, off);
            rowL[r] = rowL[r] * alpha[r] + rs;
            rowM[r] = mnew[r];
        }
#pragma unroll
        for (int ni = 0; ni < 4; ++ni)
#pragma unroll
            for (int r = 0; r < 4; ++r) o[ni][r] *= alpha[r];
        // P: C-layout -> A-operand layout via per-wave LDS round-trip (wave-internal order)
        half8 ap = *(const half8*)&Pl[wave][l16][quad * 8];
#pragma unroll
        for (int ni = 0; ni < 4; ++ni) {
            const _Float16* Vp = Vt + (size_t)(h * DK + ni * 16 + l16) * SEQ + kt + quad * 8;
            half8 bv = *(const half8*)(Vp);
            o[ni] = MFMA16(ap, bv, o[ni]);
        }
    }

    float rinv[4];
#pragma unroll
    for (int r = 0; r < 4; ++r) rinv[r] = 1.0f / rowL[r];
#pragma unroll
    for (int ni = 0; ni < 4; ++ni) {
        int n = h * DK + ni * 16 + l16;
#pragma unroll
        for (int r = 0; r < 4; ++r) {
            int m = q0 + quad * 4 + r;
            X[(size_t)m * DM + n] = (_Float16)(o[ni][r] * rinv[r]);
        }
    }
}

extern "C" void kernel_launch(void* const* d_in, const int* in_sizes, int n_in, void* d_out,
                              int out_size, void* d_ws, size_t ws_size, hipStream_t stream) {
    const float* q  = (const float*)d_in[0];
    const float* k  = (const float*)d_in[1];
    const float* v  = (const float*)d_in[2];
    const float* wq = (const float*)d_in[3];
    const float* bq = (const float*)d_in[4];
    const float* wk = (const float*)d_in[5];
    const float* bk = (const float*)d_in[6];
    const float* wv = (const float*)d_in[7];
    const float* bv = (const float*)d_in[8];
    const float* wo = (const float*)d_in[9];
    const float* bo = (const float*)d_in[10];

    const size_t SZ_T = (size_t)SEQ * DM * sizeof(_Float16);  // 8 MB
    const size_t SZ_W = (size_t)DM * DM * sizeof(_Float16);   // 2 MB
    char* p = (char*)d_ws;
    _Float16* qh  = (_Float16*)(p);
    _Float16* kh  = (_Float16*)(p + SZ_T);
    _Float16* vh  = (_Float16*)(p + 2 * SZ_T);
    _Float16* wqh = (_Float16*)(p + 3 * SZ_T);
    _Float16* wkh = (_Float16*)(p + 3 * SZ_T + SZ_W);
    _Float16* wvh = (_Float16*)(p + 3 * SZ_T + 2 * SZ_W);
    _Float16* woh = (_Float16*)(p + 3 * SZ_T + 3 * SZ_W);
    _Float16* Qo  = (_Float16*)(p + 3 * SZ_T + 4 * SZ_W);
    _Float16* Ko  = (_Float16*)(p + 4 * SZ_T + 4 * SZ_W);
    _Float16* Vt  = (_Float16*)(p + 5 * SZ_T + 4 * SZ_W);
    _Float16* Xh  = qh;  // alias: qh dead after gemm_qkv (stream-serialized)

    cvt_all<<<dim3(4096, 7), 256, 0, stream>>>(q, k, v, wq, wk, wv, wo, qh, kh, vh, wqh, wkh,
                                               wvh, woh);
    gemm_qkv<<<dim3(32, 8, 3), 256, 0, stream>>>(qh, kh, vh, wqh, wkh, wvh, bq, bk, bv, Qo, Ko,
                                                 Vt);
    attn_kernel<<<dim3(SEQ / 64, NH), 256, 0, stream>>>(Qo, Ko, Vt, Xh);
    gemm_out<<<dim3(32, 8), 256, 0, stream>>>(Xh, woh, bo, (float*)d_out);
}

// Round 2
// 218.198 us; speedup vs baseline: 1.0067x; 1.0067x over previous
//
#include <hip/hip_runtime.h>

#define SEQ 4096
#define DM 1024
#define NH 16
#define DK 64
#define NT 10  // 32-key tiles per 16-query wave: span <= 302 < 320

typedef _Float16 half8 __attribute__((ext_vector_type(8)));
typedef _Float16 half4v __attribute__((ext_vector_type(4)));
typedef float f32x4 __attribute__((ext_vector_type(4)));

#define MFMA16(a, b, c) __builtin_amdgcn_mfma_f32_16x16x32_f16((a), (b), (c), 0, 0, 0)

// ---------------- fp32 -> fp16 conversion (7 tensors in one launch) ----------------
__global__ void cvt_all(const float* __restrict__ q, const float* __restrict__ k,
                        const float* __restrict__ v, const float* __restrict__ wq,
                        const float* __restrict__ wk, const float* __restrict__ wv,
                        const float* __restrict__ wo, _Float16* __restrict__ qh,
                        _Float16* __restrict__ kh, _Float16* __restrict__ vh,
                        _Float16* __restrict__ wqh, _Float16* __restrict__ wkh,
                        _Float16* __restrict__ wvh, _Float16* __restrict__ woh) {
    int z = blockIdx.y;
    const float* src;
    _Float16* dst;
    int n;
    switch (z) {
    case 0: src = q;  dst = qh;  n = SEQ * DM; break;
    case 1: src = k;  dst = kh;  n = SEQ * DM; break;
    case 2: src = v;  dst = vh;  n = SEQ * DM; break;
    case 3: src = wq; dst = wqh; n = DM * DM;  break;
    case 4: src = wk; dst = wkh; n = DM * DM;  break;
    case 5: src = wv; dst = wvh; n = DM * DM;  break;
    default: src = wo; dst = woh; n = DM * DM; break;
    }
    int idx = (blockIdx.x * 256 + threadIdx.x) * 4;
    if (idx >= n) return;
    float4 f = *(const float4*)(src + idx);
    half4v h;
    h[0] = (_Float16)f.x; h[1] = (_Float16)f.y; h[2] = (_Float16)f.z; h[3] = (_Float16)f.w;
    *(half4v*)(dst + idx) = h;
}

// ---------------- m97-style f16 GEMM core: C = A @ B^T + bias ----------------
// A[M,K] row-major f16, B[N,K] row-major f16 (x @ W.T), K=N=1024.
// MT: M-tile (128 or 64). N-tile fixed 128.
// mode 0: f16 out row-major, (acc+bias)*scale
// mode 1: f16 out transposed [N][M] pitch SEQ (per-head-transposed V)
// mode 2: fp32 out row-major, acc+bias
template <int MT>
__device__ __forceinline__ void gemm_core(const _Float16* __restrict__ A,
                                          const _Float16* __restrict__ B,
                                          const float* __restrict__ bias,
                                          void* __restrict__ Cout, int mode, float scale) {
    const int K = DM;
    const int N = DM;
    constexpr int MI = MT / 32;   // acc row-frags per wave
    constexpr int ACH = MT / 64;  // A staging chunks (256 lanes x 16B = 64 rows x 32 cols f16)
    __shared__ _Float16 As[MT * 32];
    __shared__ _Float16 Bs[128 * 32];
    int tid = threadIdx.x;
    int wave = tid >> 6, lane = tid & 63;
    int quad = lane >> 4, l16 = lane & 15;
    int m0 = blockIdx.x * MT;
    int n0 = blockIdx.y * 128;
    int wr = (wave >> 1) * (MT / 2);
    int wc = (wave & 1) * 64;
    f32x4 acc[MI][4] = {};

    for (int k0 = 0; k0 < K; k0 += 32) {
#pragma unroll
        for (int j = 0; j < ACH; ++j) {
            int c = j * 256 + tid;
            int row = c >> 2, cc = c & 3;
            const _Float16* ga = A + (size_t)(m0 + row) * K + k0 + cc * 8;
            __builtin_amdgcn_global_load_lds(
                (const __attribute__((address_space(1))) void*)ga,
                (__attribute__((address_space(3))) void*)(As + j * 2048 + wave * 512), 16, 0, 0);
        }
#pragma unroll
        for (int j = 0; j < 2; ++j) {
            int c = j * 256 + tid;
            int row = c >> 2, cc = c & 3;
            const _Float16* gb = B + (size_t)(n0 + row) * K + k0 + cc * 8;
            __builtin_amdgcn_global_load_lds(
                (const __attribute__((address_space(1))) void*)gb,
                (__attribute__((address_space(3))) void*)(Bs + j * 2048 + wave * 512), 16, 0, 0);
        }
        __syncthreads();
        half8 af[MI], bf[4];
#pragma unroll
        for (int mi = 0; mi < MI; ++mi)
            af[mi] = *(const half8*)&As[(wr + mi * 16 + l16) * 32 + quad * 8];
#pragma unroll
        for (int ni = 0; ni < 4; ++ni)
            bf[ni] = *(const half8*)&Bs[(wc + ni * 16 + l16) * 32 + quad * 8];
#pragma unroll
        for (int mi = 0; mi < MI; ++mi)
#pragma unroll
            for (int ni = 0; ni < 4; ++ni)
                acc[mi][ni] = MFMA16(af[mi], bf[ni], acc[mi][ni]);
        __syncthreads();
    }

    float bs[4];
#pragma unroll
    for (int ni = 0; ni < 4; ++ni) bs[ni] = bias[n0 + wc + ni * 16 + l16];

    if (mode == 0) {
        _Float16* C = (_Float16*)Cout;
#pragma unroll
        for (int mi = 0; mi < MI; ++mi)
#pragma unroll
            for (int ni = 0; ni < 4; ++ni) {
                int m = m0 + wr + mi * 16 + quad * 4;
                int n = n0 + wc + ni * 16 + l16;
#pragma unroll
                for (int r = 0; r < 4; ++r)
                    C[(size_t)(m + r) * N + n] = (_Float16)((acc[mi][ni][r] + bs[ni]) * scale);
            }
    } else if (mode == 1) {
        _Float16* C = (_Float16*)Cout;
#pragma unroll
        for (int mi = 0; mi < MI; ++mi)
#pragma unroll
            for (int ni = 0; ni < 4; ++ni) {
                int m = m0 + wr + mi * 16 + quad * 4;
                int n = n0 + wc + ni * 16 + l16;
                half4v p;
#pragma unroll
                for (int r = 0; r < 4; ++r) p[r] = (_Float16)(acc[mi][ni][r] + bs[ni]);
                *(half4v*)(C + (size_t)n * SEQ + m) = p;  // m % 4 == 0 -> 8B aligned
            }
    } else {
        float* C = (float*)Cout;
#pragma unroll
        for (int mi = 0; mi < MI; ++mi)
#pragma unroll
            for (int ni = 0; ni < 4; ++ni) {
                int m = m0 + wr + mi * 16 + quad * 4;
                int n = n0 + wc + ni * 16 + l16;
#pragma unroll
                for (int r = 0; r < 4; ++r)
                    C[(size_t)(m + r) * N + n] = acc[mi][ni][r] + bs[ni];
            }
    }
}

__global__ void gemm_qkv(const _Float16* __restrict__ qh, const _Float16* __restrict__ kh,
                         const _Float16* __restrict__ vh, const _Float16* __restrict__ wqh,
                         const _Float16* __restrict__ wkh, const _Float16* __restrict__ wvh,
                         const float* __restrict__ bq, const float* __restrict__ bk,
                         const float* __restrict__ bv, _Float16* __restrict__ Qo,
                         _Float16* __restrict__ Ko, _Float16* __restrict__ Vt) {
    int z = blockIdx.z;
    const _Float16 *A, *B;
    const float* bias;
    void* C;
    int mode;
    float scale;
    if (z == 0) { A = qh; B = wqh; bias = bq; C = Qo; mode = 0; scale = 0.125f; }  // 1/sqrt(64)
    else if (z == 1) { A = kh; B = wkh; bias = bk; C = Ko; mode = 0; scale = 1.0f; }
    else { A = vh; B = wvh; bias = bv; C = Vt; mode = 1; scale = 1.0f; }
    gemm_core<128>(A, B, bias, C, mode, scale);
}

__global__ void gemm_out(const _Float16* __restrict__ Xh, const _Float16* __restrict__ woh,
                         const float* __restrict__ bo, float* __restrict__ out) {
    gemm_core<64>(Xh, woh, bo, out, 2, 1.0f);
}

// ---------------- windowed attention, two-phase (full window in registers) ----------------
// One wave = 16 queries of one head. Q pre-scaled by 1/8. Vt is [DM][SEQ] (per-head V^T).
// No online softmax: all 10 score tiles computed with full ILP, then one mask/max/exp
// pass, then 10 independent PV tiles. Row pad 40 halves = 80B (16B-aligned b128 reads,
// quads spread over bank groups).
__global__ void __launch_bounds__(256) attn_kernel(const _Float16* __restrict__ Q,
                                                   const _Float16* __restrict__ K,
                                                   const _Float16* __restrict__ Vt,
                                                   _Float16* __restrict__ X) {
    __shared__ _Float16 Pl[4][NT][16][40];
    int tid = threadIdx.x;
    int wave = tid >> 6, lane = tid & 63;
    int quad = lane >> 4, l16 = lane & 15;
    int h = blockIdx.y;
    int q0 = blockIdx.x * 64 + wave * 16;

    const _Float16* Qp = Q + (size_t)(q0 + l16) * DM + h * DK + quad * 8;
    half8 aq0 = *(const half8*)(Qp);
    half8 aq1 = *(const half8*)(Qp + 32);

    int kstart = (q0 > 127) ? ((q0 - 127) & ~31) : 0;

    // Phase 1: all QK^T scores into registers (40 independent MFMAs, loads fully in flight)
    f32x4 s[NT][2];
#pragma unroll
    for (int t = 0; t < NT; ++t) {
        int kt = kstart + t * 32;
#pragma unroll
        for (int cf = 0; cf < 2; ++cf) {
            int krow = kt + cf * 16 + l16;
            int kc = krow < SEQ ? krow : SEQ - 1;  // clamp; masked later
            const _Float16* Kp = K + (size_t)kc * DM + h * DK + quad * 8;
            half8 b0 = *(const half8*)(Kp);
            half8 b1 = *(const half8*)(Kp + 32);
            f32x4 z = {};
            z = MFMA16(aq0, b0, z);
            z = MFMA16(aq1, b1, z);
            s[t][cf] = z;
        }
    }

    // Phase 2: mask, row-max, exp, row-sum, P -> LDS (fp16, A-operand staging)
#pragma unroll
    for (int t = 0; t < NT; ++t)
#pragma unroll
        for (int cf = 0; cf < 2; ++cf) {
            int key = kstart + t * 32 + cf * 16 + l16;
#pragma unroll
            for (int r = 0; r < 4; ++r) {
                int row = q0 + quad * 4 + r;
                bool valid = (key >= row - 127) && (key <= row + 128) && (key < SEQ);
                if (!valid) s[t][cf][r] = -1e30f;
            }
        }

    float rinv[4];
#pragma unroll
    for (int r = 0; r < 4; ++r) {
        float m = -1e30f;
#pragma unroll
        for (int t = 0; t < NT; ++t) m = fmaxf(m, fmaxf(s[t][0][r], s[t][1][r]));
#pragma unroll
        for (int off = 1; off < 16; off <<= 1) m = fmaxf(m, __shfl_xor(m, off));
        float sum = 0.f;
#pragma unroll
        for (int t = 0; t < NT; ++t) {
            float p0 = __expf(s[t][0][r] - m);  // masked -> exp(-1e30-m) = 0
            float p1 = __expf(s[t][1][r] - m);
            Pl[wave][t][quad * 4 + r][l16] = (_Float16)p0;
            Pl[wave][t][quad * 4 + r][l16 + 16] = (_Float16)p1;
            sum += p0 + p1;
        }
#pragma unroll
        for (int off = 1; off < 16; off <<= 1) sum += __shfl_xor(sum, off);
        rinv[r] = 1.0f / sum;
    }

    // Phase 3: PV (4 independent accumulation chains, per-wave LDS buffers, no barrier)
    f32x4 o[4] = {};
#pragma unroll
    for (int t = 0; t < NT; ++t) {
        half8 ap = *(const half8*)&Pl[wave][t][l16][quad * 8];
        int vcol = kstart + t * 32 + quad * 8;
        int vc = vcol < SEQ ? vcol : 0;  // 8-col groups never straddle SEQ; P=0 there
#pragma unroll
        for (int ni = 0; ni < 4; ++ni) {
            const _Float16* Vp = Vt + (size_t)(h * DK + ni * 16 + l16) * SEQ + vc;
            half8 bv = *(const half8*)(Vp);
            o[ni] = MFMA16(ap, bv, o[ni]);
        }
    }

#pragma unroll
    for (int ni = 0; ni < 4; ++ni) {
        int n = h * DK + ni * 16 + l16;
#pragma unroll
        for (int r = 0; r < 4; ++r) {
            int m = q0 + quad * 4 + r;
            X[(size_t)m * DM + n] = (_Float16)(o[ni][r] * rinv[r]);
        }
    }
}

extern "C" void kernel_launch(void* const* d_in, const int* in_sizes, int n_in, void* d_out,
                              int out_size, void* d_ws, size_t ws_size, hipStream_t stream) {
    const float* q  = (const float*)d_in[0];
    const float* k  = (const float*)d_in[1];
    const float* v  = (const float*)d_in[2];
    const float* wq = (const float*)d_in[3];
    const float* bq = (const float*)d_in[4];
    const float* wk = (const float*)d_in[5];
    const float* bk = (const float*)d_in[6];
    const float* wv = (const float*)d_in[7];
    const float* bv = (const float*)d_in[8];
    const float* wo = (const float*)d_in[9];
    const float* bo = (const float*)d_in[10];

    const size_t SZ_T = (size_t)SEQ * DM * sizeof(_Float16);  // 8 MB
    const size_t SZ_W = (size_t)DM * DM * sizeof(_Float16);   // 2 MB
    char* p = (char*)d_ws;
    _Float16* qh  = (_Float16*)(p);
    _Float16* kh  = (_Float16*)(p + SZ_T);
    _Float16* vh  = (_Float16*)(p + 2 * SZ_T);
    _Float16* wqh = (_Float16*)(p + 3 * SZ_T);
    _Float16* wkh = (_Float16*)(p + 3 * SZ_T + SZ_W);
    _Float16* wvh = (_Float16*)(p + 3 * SZ_T + 2 * SZ_W);
    _Float16* woh = (_Float16*)(p + 3 * SZ_T + 3 * SZ_W);
    _Float16* Qo  = (_Float16*)(p + 3 * SZ_T + 4 * SZ_W);
    _Float16* Ko  = (_Float16*)(p + 4 * SZ_T + 4 * SZ_W);
    _Float16* Vt  = (_Float16*)(p + 5 * SZ_T + 4 * SZ_W);
    _Float16* Xh  = qh;  // alias: qh dead after gemm_qkv (stream-serialized)

    cvt_all<<<dim3(4096, 7), 256, 0, stream>>>(q, k, v, wq, wk, wv, wo, qh, kh, vh, wqh, wkh,
                                               wvh, woh);
    gemm_qkv<<<dim3(32, 8, 3), 256, 0, stream>>>(qh, kh, vh, wqh, wkh, wvh, bq, bk, bv, Qo, Ko,
                                                 Vt);
    attn_kernel<<<dim3(SEQ / 64, NH), 256, 0, stream>>>(Qo, Ko, Vt, Xh);
    gemm_out<<<dim3(64, 8), 256, 0, stream>>>(Xh, woh, bo, (float*)d_out);
}